// Round 14
// baseline (340.009 us; speedup 1.0000x reference)
//
#include <hip/hip_runtime.h>
#include <hip/hip_bf16.h>

#define HW 65536
#define KPAD 584   // Vt row stride (bf16): 1168B rows, 16B-aligned

typedef __attribute__((ext_vector_type(8))) short bf8;
typedef __attribute__((ext_vector_type(4))) float f4;

__device__ __forceinline__ unsigned short f2b(float x) {   // RNE float->bf16
  unsigned int u = __float_as_uint(x);
  unsigned int r = (u + 0x7fff + ((u >> 16) & 1)) >> 16;
  return (unsigned short)r;
}
__device__ __forceinline__ unsigned int pk2(float lo, float hi) {  // trunc pack 2xbf16
  return (__float_as_uint(hi) & 0xffff0000u) | (__float_as_uint(lo) >> 16);
}
__device__ __forceinline__ float ex2(float x) { return __builtin_amdgcn_exp2f(x); }

// ================= device bodies =================
__device__ __forceinline__ void stem_front_body(
    int bx, int t, const float* __restrict__ depth,
    const float* __restrict__ cw1, const float* __restrict__ cb1,
    const float* __restrict__ cw2, const float* __restrict__ cb2,
    float* __restrict__ t2) {
  int p = bx * 256 + t;
  int y = p >> 8, x = p & 255;
  float in9[9];
#pragma unroll
  for (int ky = 0; ky < 3; ky++)
#pragma unroll
    for (int kx = 0; kx < 3; kx++) {
      int yy = y + ky - 1, xx = x + kx - 1;
      bool ok = ((unsigned)yy < 256u) && ((unsigned)xx < 256u);
      in9[ky*3+kx] = ok ? depth[yy*256+xx] : 0.f;
    }
  float t1[8];
#pragma unroll
  for (int o = 0; o < 8; o++) {
    float s = cb1[o];
#pragma unroll
    for (int i = 0; i < 9; i++) s += in9[i] * cw1[o*9+i];
    t1[o] = fmaxf(s, 0.f);
  }
#pragma unroll
  for (int o = 0; o < 16; o++) {
    float s = cb2[o];
#pragma unroll
    for (int ci = 0; ci < 8; ci++) s += t1[ci] * cw2[o*8+ci];
    t2[o*HW + p] = fmaxf(s, 0.f);
  }
}

// bias layout per (hd,qt): [kb=key/4][q16][r=key&3]; pre-scaled by 1/ln2 with -8 shift
__device__ __forceinline__ void bias_body(
    int bx, int t, const int* __restrict__ rpi,
    const float* __restrict__ rpb, float* __restrict__ biasT) {
  int idx = bx*256 + t;        // 1152*256 = 294912 exact
  int hd = idx / 147456;
  int rem = idx - hd*147456;
  int qt = rem / 9216;
  int r2 = rem - qt*9216;
  int kb = r2 >> 6;
  int q16 = (r2 >> 2) & 15;
  int r = r2 & 3;
  int key = kb*4 + r;
  int qq = qt*16 + q16;
  biasT[idx] = (rpb[rpi[qq*576 + key]*2 + hd] - 8.0f) * 1.44269504f;
}

// 16-output LN(+IN) matmul slab — weights/coefs via UNIFORM global reads (s_load),
// zero LDS, zero barriers.
// roles: 0/1: q1 = LN(x)@wq cols 0/16        2..5: kv2 = LN(x)@wkv cols 16c
//        6/7: q2 = LN(IN(t4))@wq cols 0/16   8..11: kv1 = LN(IN(t4))@wkv cols 16c
__device__ __forceinline__ void lnmm16_body(
    int role, int bx, int t,
    const float* __restrict__ x, const float* __restrict__ t4,
    const float* __restrict__ part,
    const float* __restrict__ ig, const float* __restrict__ ib,
    const float* __restrict__ n1g, const float* __restrict__ n1b,
    const float* __restrict__ wq, const float* __restrict__ bq,
    const float* __restrict__ wkv, const float* __restrict__ bkv,
    float* q1, float* kv1, float* q2, float* kv2) {
  const float *src, *wm, *bo; float* dst;
  int wstride, wcol; bool ain;
  if (role < 6) { src = x;  ain = false; } else { src = t4; ain = true; }
  switch (role) {
    default:
    case 0:  wm=wq;  wstride=32; wcol=0;  bo=bq;  dst=q1;               break;
    case 1:  wm=wq;  wstride=32; wcol=16; bo=bq;  dst=q1+16*HW;         break;
    case 2: case 3: case 4: case 5:
             wm=wkv; wstride=64; wcol=16*(role-2); bo=bkv; dst=kv2+16*(role-2)*HW; break;
    case 6:  wm=wq;  wstride=32; wcol=0;  bo=bq;  dst=q2;               break;
    case 7:  wm=wq;  wstride=32; wcol=16; bo=bq;  dst=q2+16*HW;         break;
    case 8: case 9: case 10: case 11:
             wm=wkv; wstride=64; wcol=16*(role-8); bo=bkv; dst=kv1+16*(role-8)*HW; break;
  }
  int p = bx*256 + t;
  float v[32]; float s = 0.f;
  if (ain) {
#pragma unroll
    for (int c = 0; c < 32; c++) {
      float m = part[c] * (1.f/65536.f);                 // uniform -> scalar
      float var = part[32+c] * (1.f/65536.f) - m*m;
      float a = rsqrtf(var + 1e-5f) * ig[c];
      float b = ib[c] - m*a;
      v[c] = src[c*HW+p]*a + b; s += v[c];
    }
  } else {
#pragma unroll
    for (int c = 0; c < 32; c++) { v[c] = src[c*HW+p]; s += v[c]; }
  }
  float m = s * 0.03125f;
  float ss = 0.f;
#pragma unroll
  for (int c = 0; c < 32; c++) { float d = v[c]-m; ss += d*d; }
  float rs = rsqrtf(ss*0.03125f + 1e-5f);
  float acc[16];
#pragma unroll
  for (int j = 0; j < 16; j++) acc[j] = bo[wcol + j];    // uniform
#pragma unroll
  for (int c = 0; c < 32; c++) {
    float ln = (v[c]-m)*rs*n1g[c] + n1b[c];              // uniform coefs
    const float* w = &wm[c*wstride + wcol];
#pragma unroll
    for (int j = 0; j < 16; j++) acc[j] += ln * w[j];    // uniform -> s_load
  }
#pragma unroll
  for (int j = 0; j < 16; j++) dst[j*HW+p] = acc[j];
}

// ================= kernels =================
// flat mega-launch: [0,256) stem | [256,1408) bias | [1408, 1408+nln*256) lnmm16 roles
__global__ __launch_bounds__(256) void k_misc(
    const float* __restrict__ depth,
    const float* __restrict__ cw1, const float* __restrict__ cb1,
    const float* __restrict__ cw2, const float* __restrict__ cb2,
    float* __restrict__ t2,
    const int* __restrict__ rpi, const float* __restrict__ rpb, float* __restrict__ biasT,
    const float* __restrict__ x, const float* __restrict__ t4, const float* __restrict__ part,
    const float* __restrict__ ig, const float* __restrict__ ib,
    const float* __restrict__ n1g, const float* __restrict__ n1b,
    const float* __restrict__ wq, const float* __restrict__ bq,
    const float* __restrict__ wkv, const float* __restrict__ bkv,
    float* q1, float* kv1, float* q2, float* kv2) {
  int id = blockIdx.x, t = threadIdx.x;
  if (id < 256) { stem_front_body(id, t, depth, cw1, cb1, cw2, cb2, t2); return; }
  if (id < 1408) { bias_body(id - 256, t, rpi, rpb, biasT); return; }
  int r = id - 1408;
  lnmm16_body(r >> 8, r & 255, t,
              x, t4, part, ig, ib, n1g, n1b, wq, bq, wkv, bkv, q1, kv1, q2, kv2);
}

__global__ __launch_bounds__(256) void k_lnmmB(
    const float* __restrict__ x, const float* __restrict__ t4, const float* __restrict__ part,
    const float* __restrict__ ig, const float* __restrict__ ib,
    const float* __restrict__ n1g, const float* __restrict__ n1b,
    const float* __restrict__ wq, const float* __restrict__ bq,
    const float* __restrict__ wkv, const float* __restrict__ bkv,
    float* q1, float* kv1, float* q2, float* kv2, int ybase) {
  lnmm16_body(ybase + blockIdx.y, blockIdx.x, threadIdx.x,
              x, t4, part, ig, ib, n1g, n1b, wq, bq, wkv, bkv, q1, kv1, q2, kv2);
}

// fused conv3(16->16,k3,relu) + conv4 half (16 outputs) + instance-norm partial stats.
__global__ __launch_bounds__(256) void k_conv34(
    const float* __restrict__ t2,
    const float* __restrict__ cw3, const float* __restrict__ cb3,
    const float* __restrict__ cw4, const float* __restrict__ cb4,
    float* __restrict__ t4, float* __restrict__ part) {
  __shared__ float sh[128];   // [kind 0/1][o 0..15][wave 0..3]
  int t = threadIdx.x;
  int bx = blockIdx.x, half = blockIdx.y;
  int p = bx*256 + t;
  int y = p >> 8, x = p & 255;
  float a3[16];
#pragma unroll
  for (int o = 0; o < 16; o++) a3[o] = cb3[o];
#pragma unroll 1
  for (int tap = 0; tap < 9; tap++) {
    int ky = tap/3 - 1, kx = tap - (tap/3)*3 - 1;
    int yy = y+ky, xx = x+kx;
    bool ok = ((unsigned)yy < 256u) && ((unsigned)xx < 256u);
    int pp = yy*256+xx;
#pragma unroll
    for (int ci = 0; ci < 16; ci++) {
      float v = ok ? t2[ci*HW+pp] : 0.f;
#pragma unroll
      for (int o = 0; o < 16; o++)
        a3[o] += v * cw3[o*144 + ci*9 + tap];   // uniform -> s_load
    }
  }
#pragma unroll
  for (int o = 0; o < 16; o++) a3[o] = fmaxf(a3[o], 0.f);
  int wave = t >> 6;
#pragma unroll 1
  for (int o = 0; o < 16; o++) {
    int oo = half*16 + o;
    float s = cb4[oo];
#pragma unroll
    for (int ci = 0; ci < 16; ci++) s += a3[ci]*cw4[oo*16+ci];
    t4[oo*HW+p] = s;
    float sum = s, ssq = s*s;
#pragma unroll
    for (int off = 32; off > 0; off >>= 1) {
      sum += __shfl_down(sum, off, 64);
      ssq += __shfl_down(ssq, off, 64);
    }
    if ((t & 63) == 0) { sh[o*4 + wave] = sum; sh[64 + o*4 + wave] = ssq; }
  }
  __syncthreads();
  if (t < 32) {
    int o = t & 15, kind = t >> 4;
    float v = sh[kind*64 + o*4+0] + sh[kind*64 + o*4+1]
            + sh[kind*64 + o*4+2] + sh[kind*64 + o*4+3];
    atomicAdd(&part[kind*32 + half*16 + o], v);
  }
}

// ---------------- MFMA attention: S^T form, 4 q-tiles, register-Q, 4 blocks/CU ----------------
__global__ __launch_bounds__(256, 4) void k_attn(
    const float* __restrict__ qA, const float* __restrict__ kvA, float* __restrict__ aoA,
    const float* __restrict__ qB, const float* __restrict__ kvB, float* __restrict__ aoB,
    const float* __restrict__ biasT) {
  __shared__ __align__(16) unsigned short Ks[576*16];   // [key][d]  18432B
  __shared__ __align__(16) unsigned short Vt[16*KPAD];  // [d][key-permuted] 18688B

  const float* q  = blockIdx.y ? qB  : qA;
  const float* kv = blockIdx.y ? kvB : kvA;
  float* ao       = blockIdx.y ? aoB : aoA;

  int id = blockIdx.x;                       // 0..511
  int lin = ((id & 7) << 6) | (id >> 3);     // XCD swizzle
  int wi = lin >> 1, hd = lin & 1;
  int wy = wi >> 4, wx = wi & 15;
  int t = threadIdx.x;
  int by = wy*16 - 4, bx = wx*16 - 4;
  int kbase = hd*16*HW, vbase = (32 + hd*16)*HW;

  int wave = t >> 6, lane = t & 63;
  int quad = lane >> 4, l16 = lane & 15;
  const bf8 zero8 = {0,0,0,0,0,0,0,0};

  bf8 qf[4];
#pragma unroll
  for (int qi = 0; qi < 4; qi++) {
    int qt = wave*4 + qi;
    if (quad < 2) {
      int prow = (wy*16 + qt)*256 + wx*16 + l16;
      unsigned short qtmp[8];
#pragma unroll
      for (int j = 0; j < 8; j++)
        qtmp[j] = f2b(q[(hd*16 + quad*8 + j)*HW + prow] * 0.360673503f); // 0.25/ln2
      qf[qi] = *(const bf8*)qtmp;
    } else {
      qf[qi] = zero8;
    }
  }

  for (int e = t; e < 576; e += 256) {
    int dy = e / 24, dx = e - dy*24;
    int yy = by + dy, xx = bx + dx;
    bool ok = ((unsigned)yy < 256u) && ((unsigned)xx < 256u);
    int pp = yy*256 + xx;
    int off = e & 31;
    int ppos = ((off & 12) << 1) + ((off >> 4) << 2) + (off & 3);
    int vcol = (e & ~31) + ppos;
    unsigned short tk[16];
#pragma unroll
    for (int i = 0; i < 16; i++) {
      float kvl = ok ? kv[kbase + i*HW + pp] : 0.f;
      float vvl = ok ? kv[vbase + i*HW + pp] : 0.f;
      tk[i] = f2b(kvl);
      Vt[i*KPAD + vcol] = f2b(vvl);
    }
    *(uint4*)&Ks[e*16]     = *(uint4*)&tk[0];
    *(uint4*)&Ks[e*16 + 8] = *(uint4*)&tk[8];
  }
  __syncthreads();

  f4 oacc[4];
  float lr[4];
  const float* bb[4];
#pragma unroll
  for (int qi = 0; qi < 4; qi++) {
    int qt = wave*4 + qi;
    oacc[qi] = (f4){0.f,0.f,0.f,0.f};
    lr[qi] = 0.f;
    bb[qi] = biasT + (hd*16 + qt)*9216 + quad*64 + l16*4;
  }

#pragma unroll 2
  for (int kt2 = 0; kt2 < 18; kt2++) {
    int k0 = kt2 * 32;
    bf8 kf0 = zero8, kf1 = zero8;
    if (quad < 2) {
      kf0 = *(const bf8*)&Ks[(k0 + l16)*16 + quad*8];
      kf1 = *(const bf8*)&Ks[(k0 + 16 + l16)*16 + quad*8];
    }
    bf8 vf = *(const bf8*)&Vt[l16*KPAD + k0 + quad*8];
#pragma unroll
    for (int qi = 0; qi < 4; qi++) {
      f4 b0 = *(const f4*)&bb[qi][k0*16];
      f4 b1 = *(const f4*)&bb[qi][(k0+16)*16];
      f4 s0 = __builtin_amdgcn_mfma_f32_16x16x32_bf16(kf0, qf[qi], b0, 0, 0, 0);
      f4 s1 = __builtin_amdgcn_mfma_f32_16x16x32_bf16(kf1, qf[qi], b1, 0, 0, 0);
      float p0[4], p1[4];
#pragma unroll
      for (int r = 0; r < 4; r++) {
        p0[r] = ex2(s0[r]);
        p1[r] = ex2(s1[r]);
        lr[qi] += p0[r] + p1[r];
      }
      union { unsigned int u[4]; bf8 v; } P;
      P.u[0] = pk2(p0[0], p0[1]); P.u[1] = pk2(p0[2], p0[3]);
      P.u[2] = pk2(p1[0], p1[1]); P.u[3] = pk2(p1[2], p1[3]);
      oacc[qi] = __builtin_amdgcn_mfma_f32_16x16x32_bf16(P.v, vf, oacc[qi], 0, 0, 0);
    }
  }
#pragma unroll
  for (int qi = 0; qi < 4; qi++) {
    lr[qi] += __shfl_xor(lr[qi], 16, 64);
    lr[qi] += __shfl_xor(lr[qi], 32, 64);
  }
#pragma unroll
  for (int qi = 0; qi < 4; qi++) {
    int qt = wave*4 + qi;
#pragma unroll
    for (int r = 0; r < 4; r++) {
      float lv = __shfl(lr[qi], quad*4 + r, 64);
      int qw = qt*16 + quad*4 + r;
      ao[(hd*16 + l16)*HW + (wy*16 + (qw >> 4))*256 + wx*16 + (qw & 15)] = oacc[qi][r] / lv;
    }
  }
}

// ---------------- proj+shortcut+LN+MLP — weights via UNIFORM global reads (s_load),
// zero LDS. ONE ocab per block. ----------------
__global__ __launch_bounds__(256) void k_projmlp(
    const float* __restrict__ ao1, const float* __restrict__ ao2,
    const float* __restrict__ x, const float* __restrict__ t4,
    const float* __restrict__ part,
    const float* __restrict__ ig, const float* __restrict__ ib,
    const float* __restrict__ wp, const float* __restrict__ bp,
    const float* __restrict__ n2g, const float* __restrict__ n2b,
    const float* __restrict__ mw1, const float* __restrict__ mb1,
    const float* __restrict__ mw2, const float* __restrict__ mb2,
    float* __restrict__ o1, float* __restrict__ o2, int obase) {
  int oc = blockIdx.y + obase;
  const float* ao = oc ? ao2 : ao1;
  float* dst      = oc ? o2  : o1;
  int t = threadIdx.x;
  int p = blockIdx.x*256 + t;
  float acc[32];
#pragma unroll
  for (int j = 0; j < 32; j++) acc[j] = bp[j];            // uniform
#pragma unroll
  for (int c = 0; c < 32; c++) {
    float vc = ao[c*HW+p];
    const float* w = &wp[c*32];
#pragma unroll
    for (int j = 0; j < 32; j++) acc[j] += vc * w[j];     // uniform -> s_load
  }
  if (oc == 0) {
#pragma unroll
    for (int j = 0; j < 32; j++) acc[j] += x[j*HW+p];
  } else {
#pragma unroll
    for (int j = 0; j < 32; j++) {
      float m = part[j] * (1.f/65536.f);                  // uniform
      float var = part[32+j] * (1.f/65536.f) - m*m;
      float a = rsqrtf(var + 1e-5f) * ig[j];
      acc[j] += t4[j*HW+p]*a + (ib[j] - m*a);
    }
  }
  float s = 0.f;
#pragma unroll
  for (int j = 0; j < 32; j++) s += acc[j];
  float m = s * 0.03125f;
  float ss = 0.f;
#pragma unroll
  for (int j = 0; j < 32; j++) { float d = acc[j]-m; ss += d*d; }
  float rs = rsqrtf(ss*0.03125f + 1e-5f);
  float r[32];
#pragma unroll
  for (int j = 0; j < 32; j++) r[j] = mb2[j];             // uniform
#pragma unroll 1
  for (int half = 0; half < 2; half++) {
    float h[32];
#pragma unroll
    for (int k = 0; k < 32; k++) h[k] = mb1[half*32 + k];
#pragma unroll
    for (int c = 0; c < 32; c++) {
      float ln = (acc[c] - m) * rs * n2g[c] + n2b[c];     // uniform coefs
      const float* w = &mw1[c*64 + half*32];
#pragma unroll
      for (int k = 0; k < 32; k++) h[k] += ln * w[k];     // uniform -> s_load
    }
#pragma unroll
    for (int k = 0; k < 32; k++) {
      float xx = h[k];
      float u = 0.7978845608f * (xx + 0.044715f*xx*xx*xx);
      float th = 1.f - 2.f/(1.f + __expf(2.f*u));
      h[k] = 0.5f * xx * (1.f + th);
    }
#pragma unroll
    for (int k = 0; k < 32; k++) {
      float hk = h[k];
      const float* w = &mw2[(half*32 + k)*32];
#pragma unroll
      for (int j = 0; j < 32; j++) r[j] += hk * w[j];     // uniform -> s_load
    }
  }
#pragma unroll
  for (int j = 0; j < 32; j++) dst[j*HW + p] = acc[j] + r[j];
}

// ---------------- final: out = o1 + o2 + x (o1 aliases out) ----------------
__global__ __launch_bounds__(256) void k_final(
    const float* o1, const float* __restrict__ o2,
    const float* __restrict__ x, float* out) {
  int i = blockIdx.x*256 + threadIdx.x;
  float4 a = ((const float4*)o1)[i];
  float4 b = ((const float4*)o2)[i];
  float4 c = ((const float4*)x)[i];
  float4 r;
  r.x = a.x + b.x + c.x; r.y = a.y + b.y + c.y;
  r.z = a.z + b.z + c.z; r.w = a.w + b.w + c.w;
  ((float4*)out)[i] = r;
}

extern "C" void kernel_launch(void* const* d_in, const int* in_sizes, int n_in,
                              void* d_out, int out_size, void* d_ws, size_t ws_size,
                              hipStream_t stream) {
  const float* x    = (const float*)d_in[0];
  const float* depth= (const float*)d_in[1];
  const int*   rpi  = (const int*)d_in[2];
  const float* cw1  = (const float*)d_in[3],  *cb1 = (const float*)d_in[4];
  const float* cw2  = (const float*)d_in[5],  *cb2 = (const float*)d_in[6];
  const float* cw3  = (const float*)d_in[7],  *cb3 = (const float*)d_in[8];
  const float* cw4  = (const float*)d_in[9],  *cb4 = (const float*)d_in[10];
  const float* in_g = (const float*)d_in[11], *in_b = (const float*)d_in[12];
  const float* n1g  = (const float*)d_in[13], *n1b = (const float*)d_in[14];
  const float* wq   = (const float*)d_in[15], *bq  = (const float*)d_in[16];
  const float* wkv  = (const float*)d_in[17], *bkv = (const float*)d_in[18];
  const float* rpb  = (const float*)d_in[19];
  const float* wp   = (const float*)d_in[20], *bp  = (const float*)d_in[21];
  const float* n2g  = (const float*)d_in[22], *n2b = (const float*)d_in[23];
  const float* mw1  = (const float*)d_in[24], *mb1 = (const float*)d_in[25];
  const float* mw2  = (const float*)d_in[26], *mb2 = (const float*)d_in[27];

  float* W   = (float*)d_ws;
  float* o1  = (float*)d_out;

  bool big = ws_size >= (size_t)85100000;   // merged path needs ~85.07 MB

  if (big) {
    float* t4    = W;
    float* q1    = W + 2097152;
    float* q2    = W + 4194304;
    float* kv1   = W + 6291456;
    float* kv2   = W + 10485760;
    float* ao1   = W + 14680064;
    float* ao2   = W + 16777216;
    float* o2    = W + 18874368;
    float* biasT = W + 20971520;         // 294912
    float* part  = W + 21266432;         // 64 floats (stats accumulators)
    float* t2 = ao1;                     // stem temp aliases ao1 (dead by attn)

    hipMemsetAsync(part, 0, 64*sizeof(float), stream);
    k_misc   <<<2944, 256, 0, stream>>>(depth, cw1, cb1, cw2, cb2, t2,
                                        rpi, rpb, biasT,
                                        x, t4, part, in_g, in_b, n1g, n1b,
                                        wq, bq, wkv, bkv, q1, kv1, q2, kv2);
    k_conv34 <<<dim3(256,2), 256, 0, stream>>>(t2, cw3, cb3, cw4, cb4, t4, part);
    k_lnmmB  <<<dim3(256,6), 256, 0, stream>>>(x, t4, part, in_g, in_b, n1g, n1b,
                                               wq, bq, wkv, bkv, q1, kv1, q2, kv2, 6);
    k_attn   <<<dim3(512,2), 256, 0, stream>>>(q1, kv1, ao1, q2, kv2, ao2, biasT);
    k_projmlp<<<dim3(256,2), 256, 0, stream>>>(ao1, ao2, x, t4, part, in_g, in_b,
                                               wp, bp, n2g, n2b, mw1, mb1, mw2, mb2,
                                               o1, o2, 0);
    k_final  <<<2048, 256, 0, stream>>>(o1, o2, x, o1);
  } else {
    // serial fallback, ~51.5 MB
    float* t4    = W;
    float* q1    = W + 2097152;
    float* kv1   = W + 4194304;          // 4M
    float* ao1   = W + 8388608;
    float* o2    = W + 10485760;
    float* biasT = W + 12582912;
    float* part  = W + 12877824;
    float* t2 = ao1;

    hipMemsetAsync(part, 0, 64*sizeof(float), stream);
    k_misc   <<<1920, 256, 0, stream>>>(depth, cw1, cb1, cw2, cb2, t2,
                                        rpi, rpb, biasT,
                                        x, t4, part, in_g, in_b, n1g, n1b,
                                        wq, bq, wkv, bkv, q1, kv1, q1, kv1);
    k_conv34 <<<dim3(256,2), 256, 0, stream>>>(t2, cw3, cb3, cw4, cb4, t4, part);
    k_lnmmB  <<<dim3(256,4), 256, 0, stream>>>(x, t4, part, in_g, in_b, n1g, n1b,
                                               wq, bq, wkv, bkv, q1, kv1, q1, kv1, 8);
    k_attn   <<<dim3(512,1), 256, 0, stream>>>(q1, kv1, ao1, q1, kv1, ao1, biasT);
    k_projmlp<<<dim3(256,1), 256, 0, stream>>>(ao1, ao1, x, t4, part, in_g, in_b,
                                               wp, bp, n2g, n2b, mw1, mb1, mw2, mb2,
                                               o1, o2, 0);
    k_lnmmB  <<<dim3(256,6), 256, 0, stream>>>(x, t4, part, in_g, in_b, n1g, n1b,
                                               wq, bq, wkv, bkv, q1, kv1, q1, kv1, 2);
    k_attn   <<<dim3(512,1), 256, 0, stream>>>(q1, kv1, ao1, q1, kv1, ao1, biasT);
    k_projmlp<<<dim3(256,1), 256, 0, stream>>>(ao1, ao1, x, t4, part, in_g, in_b,
                                               wp, bp, n2g, n2b, mw1, mb1, mw2, mb2,
                                               o1, o2, 1);
    k_final  <<<2048, 256, 0, stream>>>(o1, o2, x, o1);
  }
}